// Round 6
// baseline (719.864 us; speedup 1.0000x reference)
//
#include <hip/hip_runtime.h>
#include <hip/hip_bf16.h>

typedef __hip_bfloat16 bf16;

static constexpr int BSZ  = 8;
static constexpr int L    = 4096;
static constexpr int DIMC = 256;
static constexpr int HID  = 512;
static constexpr int NCH  = 64;   // scan chunks
static constexpr int CLEN = 64;   // steps per chunk
static constexpr int MROWS = BSZ * L; // 32768

typedef __attribute__((ext_vector_type(8))) short bf16x8;
typedef __attribute__((ext_vector_type(4))) short short4v;
typedef __attribute__((ext_vector_type(4))) float f32x4;

__device__ __forceinline__ short f2b(float f) {
    return __builtin_bit_cast(short, __float2bfloat16(f));
}
__device__ __forceinline__ float b2f(bf16 v) { return __bfloat162float(v); }
__device__ __forceinline__ float s2f(short s) {
    return __bfloat162float(__builtin_bit_cast(bf16, s));
}
__device__ __forceinline__ void gload_lds16(const void* g, void* l) {
    __builtin_amdgcn_global_load_lds(
        (const __attribute__((address_space(1))) unsigned int*)g,
        (__attribute__((address_space(3))) unsigned int*)l, 16, 0, 0);
}

// ---------------------------------------------------------------- gray mean
__global__ void gray_kernel(const float* __restrict__ x, float* __restrict__ gray) {
    int gid = blockIdx.x * blockDim.x + threadIdx.x;
    int wid = gid >> 6, lane = gid & 63;
    if (wid >= MROWS) return;
    float4 f = *(const float4*)(x + (size_t)wid * DIMC + lane * 4);
    float s = f.x + f.y + f.z + f.w;
    for (int o = 32; o; o >>= 1) s += __shfl_down(s, o);
    if (lane == 0) gray[wid] = s * (1.f / 256.f);
}

// ------------------------------------------------- sobel/laplacian + fusion
__global__ void grad_kernel(const float* __restrict__ gray, float* __restrict__ gm,
                            const float* __restrict__ fw) {
    int p = blockIdx.x * blockDim.x + threadIdx.x;
    if (p >= MROWS) return;
    int b = p >> 12, pp = p & 4095, h = pp >> 6, w = pp & 63;
    const float* g = gray + ((size_t)b << 12);
    auto G = [&](int hh, int ww) -> float {
        if (hh < 0 || hh > 63 || ww < 0 || ww > 63) return 0.f;
        return g[(hh << 6) + ww];
    };
    float g00=G(h-1,w-1), g01=G(h-1,w), g02=G(h-1,w+1);
    float g10=G(h,  w-1), g11=G(h,  w), g12=G(h,  w+1);
    float g20=G(h+1,w-1), g21=G(h+1,w), g22=G(h+1,w+1);
    float gx  = -g00 + g02 - 2.f*g10 + 2.f*g12 - g20 + g22;
    float gy  = -g00 - 2.f*g01 - g02 + g20 + 2.f*g21 + g22;
    float lap = 4.f*g11 - g01 - g10 - g12 - g21;
    float v = fw[0]*gx + fw[1]*gy + fw[2]*lap;
    gm[p] = fabsf(v);
}

// ------------------------------------------------ per-batch minmax + sigmoid
__global__ __launch_bounds__(1024) void gp_kernel(float* __restrict__ gmgp,
                                                  const float* __restrict__ sc_,
                                                  const float* __restrict__ of_) {
    int b = blockIdx.x, tid = threadIdx.x;
    float v[4], lmin = 3.4e38f, lmax = -3.4e38f;
    for (int i = 0; i < 4; i++) {
        v[i] = gmgp[(b << 12) + tid + (i << 10)];
        lmin = fminf(lmin, v[i]); lmax = fmaxf(lmax, v[i]);
    }
    for (int o = 32; o; o >>= 1) {
        lmin = fminf(lmin, __shfl_xor(lmin, o));
        lmax = fmaxf(lmax, __shfl_xor(lmax, o));
    }
    __shared__ float smin[16], smax[16];
    int wid = tid >> 6, lane = tid & 63;
    if (lane == 0) { smin[wid] = lmin; smax[wid] = lmax; }
    __syncthreads();
    if (tid == 0) {
        float a = smin[0], c = smax[0];
        for (int wv = 1; wv < 16; wv++) { a = fminf(a, smin[wv]); c = fmaxf(c, smax[wv]); }
        smin[0] = a; smax[0] = c;
    }
    __syncthreads();
    float gmin = smin[0], gmax = smax[0];
    float invd = 1.f / (gmax - gmin + 1e-8f);
    float sc = sc_[0], of = of_[0];
    for (int i = 0; i < 4; i++) {
        float z = sc * ((v[i] - gmin) * invd) + of;
        gmgp[(b << 12) + tid + (i << 10)] = 1.f / (1.f + __expf(-z));
    }
}

// -------------------------------------------- stable argsort (bitonic, u64)
__global__ __launch_bounds__(1024) void sort_kernel(const float* __restrict__ gp,
                                                    int* __restrict__ idx, int* __restrict__ inv) {
    __shared__ unsigned long long keys[4096];
    int b = blockIdx.x, tid = threadIdx.x;
    for (int i = tid; i < 4096; i += 1024) {
        unsigned int fb = __float_as_uint(gp[(b << 12) + i]);
        keys[i] = ((unsigned long long)fb << 32) | (unsigned int)i;
    }
    __syncthreads();
    for (int k = 2; k <= 4096; k <<= 1) {
        for (int j = k >> 1; j > 0; j >>= 1) {
            for (int i = tid; i < 4096; i += 1024) {
                int ixj = i ^ j;
                if (ixj > i) {
                    unsigned long long a = keys[i], c = keys[ixj];
                    bool up = ((i & k) == 0);
                    if ((a > c) == up) { keys[i] = c; keys[ixj] = a; }
                }
            }
            __syncthreads();
        }
    }
    for (int i = tid; i < 4096; i += 1024) {
        int p = (int)(keys[i] & 0xffffffffULL);
        idx[(b << 12) + i] = p;
        inv[(b << 12) + p] = i;
    }
}

// ------------------------------------- fused LN: f32[C=256] -> normalized bf16
__global__ void normf_k(const float* __restrict__ src, const float* __restrict__ g,
                        const float* __restrict__ b, short* __restrict__ dst) {
    int gid = blockIdx.x * blockDim.x + threadIdx.x;
    int wid = gid >> 6, lane = gid & 63;
    if (wid >= MROWS) return;
    float4 f = *(const float4*)(src + (size_t)wid * 256 + lane * 4);
    float v[4] = {f.x, f.y, f.z, f.w};
    float s = v[0] + v[1] + v[2] + v[3];
    for (int o = 32; o; o >>= 1) s += __shfl_xor(s, o);
    float mean = s * (1.f / 256.f);
    float q = 0.f;
    for (int i = 0; i < 4; i++) { float d = v[i] - mean; q += d * d; }
    for (int o = 32; o; o >>= 1) q += __shfl_xor(q, o);
    float rstd = rsqrtf(q * (1.f / 256.f) + 1e-5f);
    short4v ov;
    for (int i = 0; i < 4; i++)
        ov[i] = f2b((v[i] - mean) * rstd * g[lane * 4 + i] + b[lane * 4 + i]);
    *(short4v*)(dst + (size_t)wid * 256 + lane * 4) = ov;
}

// ------------------------------------- fused LN: bf16[C=512] -> normalized bf16
__global__ void normb_k(const short* __restrict__ src, const float* __restrict__ g,
                        const float* __restrict__ b, short* __restrict__ dst) {
    int gid = blockIdx.x * blockDim.x + threadIdx.x;
    int wid = gid >> 6, lane = gid & 63;
    if (wid >= MROWS) return;
    bf16x8 pk = *(const bf16x8*)(src + (size_t)wid * 512 + lane * 8);
    float v[8];
    for (int i = 0; i < 8; i++) v[i] = s2f(pk[i]);
    float s = 0.f;
    for (int i = 0; i < 8; i++) s += v[i];
    for (int o = 32; o; o >>= 1) s += __shfl_xor(s, o);
    float mean = s * (1.f / 512.f);
    float q = 0.f;
    for (int i = 0; i < 8; i++) { float d = v[i] - mean; q += d * d; }
    for (int o = 32; o; o >>= 1) q += __shfl_xor(q, o);
    float rstd = rsqrtf(q * (1.f / 512.f) + 1e-5f);
    bf16x8 ov;
    for (int i = 0; i < 8; i++)
        ov[i] = f2b((v[i] - mean) * rstd * g[lane * 8 + i] + b[lane * 8 + i]);
    *(bf16x8*)(dst + (size_t)wid * 512 + lane * 8) = ov;
}

// ---------------- W_big[640][512]: rows 0:512 = dt_w @ x_proj_w[0:32,:],
//                  rows 512:544 = x_proj_w[32:64,:], rows 544:640 = 0
__global__ void wbig_k(const float* __restrict__ dtw, const float* __restrict__ xpw,
                       short* __restrict__ wd) {
    int d = blockIdx.x;        // 640
    for (int kk = threadIdx.x; kk < HID; kk += 256) {
        float s = 0.f;
        if (d < 512) {
#pragma unroll
            for (int r = 0; r < 32; r++) s += dtw[d * 32 + r] * xpw[r * HID + kk];
        } else if (d < 544) {
            s = xpw[(d - 480) * HID + kk];
        }
        wd[(size_t)d * HID + kk] = f2b(s);
    }
}

// -------------------------------- convert 4 weight matrices to bf16 (once)
__global__ void wcvt_k(const float* __restrict__ s0, const float* __restrict__ s1,
                       const float* __restrict__ s2, const float* __restrict__ s3,
                       short* __restrict__ dst) {
    int g = blockIdx.x * blockDim.x + threadIdx.x;
    if (g >= 524288) return;
    float v;
    if      (g < 131072) v = s0[g];
    else if (g < 262144) v = s1[g - 131072];
    else if (g < 393216) v = s2[g - 262144];
    else                 v = s3[g - 393216];
    dst[g] = f2b(v);
}

// ------------------------------------------------------------ MFMA bf16 GEMM
// m97-shaped: BM=BN=128, 4 waves (2x2), wave tile 64x64, K-step 32,
// global_load_lds width-16 staging (LDS layout = lane order, row-major).
enum { EP_BF = 0, EP_DELTAXBC = 1, EP_SILU = 2, EP_SCATTER = 3, EP_RESID = 4 };

template<int EP>
__global__ __launch_bounds__(256) void mgemm(
    const short* __restrict__ A, int lda, const short* __restrict__ W,
    const float* __restrict__ bias, int N, int K,
    const int* __restrict__ idx, const float* __restrict__ xres, const float* __restrict__ fres,
    float* __restrict__ outf, bf16* __restrict__ outb)
{
    __shared__ __align__(16) short As[128 * 32];
    __shared__ __align__(16) short Bs[128 * 32];

    const int t = threadIdx.x;
    const int m0 = blockIdx.y << 7, n0 = blockIdx.x << 7;
    const int w = t >> 6, lane = t & 63;
    const int wm0 = (w & 1) << 6, wn0 = (w >> 1) << 6;
    const int lrow = lane & 15, quad = lane >> 4;
    const int wbase = t & ~63;   // wave-uniform chunk base within 256

    f32x4 acc[4][4] = {};

    for (int k0 = 0; k0 < K; k0 += 32) {
        // ---- stage A & W: 512 chunks of 16B each, direct to LDS ----
#pragma unroll
        for (int s = 0; s < 2; s++) {
            int chunk = s * 256 + t;
            int r = chunk >> 2, q = chunk & 3;
            gload_lds16(A + (size_t)(m0 + r) * lda + k0 + q * 8,
                        &As[(s * 256 + wbase) * 8]);
        }
#pragma unroll
        for (int s = 0; s < 2; s++) {
            int chunk = s * 256 + t;
            int r = chunk >> 2, q = chunk & 3;
            gload_lds16(W + (size_t)(n0 + r) * K + k0 + q * 8,
                        &Bs[(s * 256 + wbase) * 8]);
        }
        __syncthreads();
        // ---- fragments + MFMA (wave 64x64: 4x4 frags) ----
        bf16x8 af[4], bfr[4];
#pragma unroll
        for (int f = 0; f < 4; f++)
            af[f] = *(const bf16x8*)&As[(wm0 + f * 16 + lrow) * 32 + quad * 8];
#pragma unroll
        for (int g = 0; g < 4; g++)
            bfr[g] = *(const bf16x8*)&Bs[(wn0 + g * 16 + lrow) * 32 + quad * 8];
#pragma unroll
        for (int f = 0; f < 4; f++)
#pragma unroll
            for (int g = 0; g < 4; g++)
                acc[f][g] = __builtin_amdgcn_mfma_f32_16x16x32_bf16(af[f], bfr[g], acc[f][g], 0, 0, 0);
        __syncthreads();
    }

    // ---- epilogue ---- C/D: col = lane&15, row = quad*4 + reg
#pragma unroll
    for (int f = 0; f < 4; f++) {
#pragma unroll
        for (int g = 0; g < 4; g++) {
#pragma unroll
            for (int reg = 0; reg < 4; reg++) {
                int r = m0 + wm0 + f * 16 + quad * 4 + reg;
                int c = n0 + wn0 + g * 16 + lrow;
                float v = acc[f][g][reg];
                if (EP == EP_DELTAXBC) {
                    if (c < 512) {
                        v += bias[c];
                        v = (v > 20.f) ? v : log1pf(__expf(v));
                        outb[(size_t)r * HID + c] = __float2bfloat16(v);
                    } else if (c < 544) {
                        outf[(size_t)r * 32 + (c - 512)] = v;
                    }
                } else {
                    if (bias) v += bias[c];
                    if (EP == EP_SILU) v = v / (1.f + __expf(-v));
                    if (EP == EP_SCATTER) {
                        int bb = r >> 12;
                        int p = idx[r];
                        size_t o = (((size_t)bb << 12) + p) * (size_t)N + c;
                        outf[o] = xres[o] + v;
                    } else if (EP == EP_RESID) {
                        size_t o = (size_t)r * N + c;
                        outf[o] = fres[o] + v;
                    } else {
                        size_t o = (size_t)r * N + c;
                        if (EP == EP_SILU || EP == EP_BF) outb[o] = __float2bfloat16(v);
                    }
                }
            }
        }
    }
}

// --------------- depthwise 3x3 CPE + gate + gather (LDS-tiled, bf16 in/out)
__global__ __launch_bounds__(256) void cpe_kernel(const bf16* __restrict__ xp,
                                                  const float* __restrict__ cw,
                                                  const float* __restrict__ cb,
                                                  const int* __restrict__ inv,
                                                  bf16* __restrict__ sx) {
    __shared__ float4 smem[8 * 325];   // 8 ch-chunks x (18*18=324 +1 pad-stride)
    const int blk = blockIdx.x;
    const int cg = blk & 15, tile = (blk >> 4) & 15, b = blk >> 8;
    const int h0 = (tile >> 2) << 4, w0 = (tile & 3) << 4;
    const int cg0 = cg << 5;
    const int t = threadIdx.x;

    for (int i = 0; i < 11; i++) {
        int lin = i * 256 + t;
        if (lin < 2592) {
            int pix = lin >> 3, c = lin & 7;
            int hh = pix / 18, ww = pix - hh * 18;
            int gh = h0 + hh - 1, gw = w0 + ww - 1;
            float4 val = {0.f, 0.f, 0.f, 0.f};
            if (gh >= 0 && gh < 64 && gw >= 0 && gw < 64) {
                short4v s = *(const short4v*)((const short*)xp +
                    ((size_t)((b << 12) + (gh << 6) + gw)) * HID + cg0 + c * 4);
                val.x = s2f(s[0]); val.y = s2f(s[1]); val.z = s2f(s[2]); val.w = s2f(s[3]);
            }
            smem[c * 325 + pix] = val;
        }
    }
    __syncthreads();

    const int c = t & 7, pg = t >> 3;
    const int ch0 = cg0 + c * 4;
    float4 wk[9], cb4;
#pragma unroll
    for (int ki = 0; ki < 9; ki++) {
        wk[ki].x = cw[(ch0 + 0) * 9 + ki];
        wk[ki].y = cw[(ch0 + 1) * 9 + ki];
        wk[ki].z = cw[(ch0 + 2) * 9 + ki];
        wk[ki].w = cw[(ch0 + 3) * 9 + ki];
    }
    cb4.x = cb[ch0]; cb4.y = cb[ch0 + 1]; cb4.z = cb[ch0 + 2]; cb4.w = cb[ch0 + 3];

    for (int k = 0; k < 8; k++) {
        int pix = pg + k * 32;
        int h = pix >> 4, w = pix & 15;
        int hp = (h + 1) * 18 + (w + 1);
        float ax = 0.f, ay = 0.f, az = 0.f, aw = 0.f;
#pragma unroll
        for (int dh = -1; dh <= 1; dh++)
#pragma unroll
            for (int dw = -1; dw <= 1; dw++) {
                float4 v = smem[c * 325 + hp + dh * 18 + dw];
                float4 wt = wk[(dh + 1) * 3 + (dw + 1)];
                ax += v.x * wt.x; ay += v.y * wt.y; az += v.z * wt.z; aw += v.w * wt.w;
            }
        ax += cb4.x; ay += cb4.y; az += cb4.z; aw += cb4.w;
        float4 xv = smem[c * 325 + hp];
        short4v g;
        g[0] = f2b(xv.x / (1.f + __expf(-ax)));
        g[1] = f2b(xv.y / (1.f + __expf(-ay)));
        g[2] = f2b(xv.z / (1.f + __expf(-az)));
        g[3] = f2b(xv.w / (1.f + __expf(-aw)));
        int pglob = (b << 12) + ((h0 + h) << 6) + (w0 + w);
        int r = inv[pglob];
        *(short4v*)((short*)sx + ((size_t)((b << 12) + r)) * HID + ch0) = g;
    }
}

// ------------------------------------------------- gC fixup on C columns
__global__ void gcfix_kernel(float* __restrict__ xdbl, const float* __restrict__ gp,
                             const float* __restrict__ gw_, const float* __restrict__ gcw,
                             const float* __restrict__ gcb) {
    int i = blockIdx.x * blockDim.x + threadIdx.x; // 8*4096*16
    int s = i & 15, t = (i >> 4) & 4095, b = i >> 16;
    float gw = gw_[0];
    float gpv = gp[(b << 12) + (s << 8) + (t >> 4)];
    int tm = t & 15;
    xdbl[(((size_t)(b << 12) + t) << 5) + 16 + s] += gw * (gpv * gcw[tm] + gcb[tm]);
}

// ------------------------------------------------------ chunked scan pass 1
__global__ __launch_bounds__(512) void scan_pass1(const bf16* __restrict__ delta,
                                                  const bf16* __restrict__ sx,
                                                  const float* __restrict__ xdbl,
                                                  const float* __restrict__ A_logs,
                                                  float* __restrict__ h_end,
                                                  float* __restrict__ sumdelta) {
    __shared__ float Bsm[CLEN][16];
    int b = blockIdx.x >> 6, c = blockIdx.x & 63, d = threadIdx.x;
    int t0 = c << 6;
    for (int i = threadIdx.x; i < CLEN * 16; i += 512) {
        int row = i >> 4, col = i & 15;
        Bsm[row][col] = xdbl[(((size_t)(b << 12) + t0 + row) << 5) + col];
    }
    __syncthreads();
    float A[16];
#pragma unroll
    for (int s = 0; s < 16; s++) A[s] = -__expf(A_logs[d * 16 + s]);
    float h[16];
#pragma unroll
    for (int s = 0; s < 16; s++) h[s] = 0.f;
    float sumd = 0.f;
    for (int t = 0; t < CLEN; t++) {
        size_t ro = (((size_t)b << 12) + t0 + t) * HID + d;
        float dlt = b2f(delta[ro]), uu = b2f(sx[ro]);
        sumd += dlt;
        float du = dlt * uu;
#pragma unroll
        for (int s = 0; s < 16; s++) h[s] = __expf(A[s] * dlt) * h[s] + du * Bsm[t][s];
    }
    int cidx = blockIdx.x;
    sumdelta[(size_t)cidx * HID + d] = sumd;
#pragma unroll
    for (int s = 0; s < 16; s++) h_end[((size_t)cidx * 16 + s) * HID + d] = h[s];
}

// --------------------------------------------------- scan chunk combination
__global__ __launch_bounds__(512) void scan_combine(const float* __restrict__ h_end,
                                                    const float* __restrict__ sumdelta,
                                                    const float* __restrict__ A_logs,
                                                    float* __restrict__ h_start) {
    int b = blockIdx.x, d = threadIdx.x;
    float A[16];
#pragma unroll
    for (int s = 0; s < 16; s++) A[s] = -__expf(A_logs[d * 16 + s]);
    float carry[16];
#pragma unroll
    for (int s = 0; s < 16; s++) carry[s] = 0.f;
    for (int c = 0; c < NCH; c++) {
        int cidx = (b << 6) + c;
        float sd = sumdelta[(size_t)cidx * HID + d];
#pragma unroll
        for (int s = 0; s < 16; s++) {
            size_t o = ((size_t)cidx * 16 + s) * HID + d;
            h_start[o] = carry[s];
            carry[s] = __expf(A[s] * sd) * carry[s] + h_end[o];
        }
    }
}

// ------------------------------------------------------ chunked scan pass 2
__global__ __launch_bounds__(512) void scan_pass2(const bf16* __restrict__ delta,
                                                  bf16* __restrict__ sxy,  // in: sx, out: y
                                                  const float* __restrict__ xdbl,
                                                  const float* __restrict__ A_logs,
                                                  const float* __restrict__ Ds,
                                                  const float* __restrict__ h_start) {
    __shared__ float BC[CLEN][32];
    int b = blockIdx.x >> 6, c = blockIdx.x & 63, d = threadIdx.x;
    int t0 = c << 6;
    for (int i = threadIdx.x; i < CLEN * 32; i += 512) {
        int row = i >> 5, col = i & 31;
        BC[row][col] = xdbl[(((size_t)(b << 12) + t0 + row) << 5) + col];
    }
    __syncthreads();
    float A[16];
#pragma unroll
    for (int s = 0; s < 16; s++) A[s] = -__expf(A_logs[d * 16 + s]);
    int cidx = blockIdx.x;
    float h[16];
#pragma unroll
    for (int s = 0; s < 16; s++) h[s] = h_start[((size_t)cidx * 16 + s) * HID + d];
    float Dd = Ds[d];
    for (int t = 0; t < CLEN; t++) {
        size_t ro = (((size_t)b << 12) + t0 + t) * HID + d;
        float dlt = b2f(delta[ro]), uu = b2f(sxy[ro]);
        float du = dlt * uu;
        float acc = uu * Dd;
#pragma unroll
        for (int s = 0; s < 16; s++) {
            h[s] = __expf(A[s] * dlt) * h[s] + du * BC[t][s];
            acc += h[s] * BC[t][16 + s];
        }
        sxy[ro] = __float2bfloat16(acc);
    }
}

// ---------------------------------------------------------------- launcher
extern "C" void kernel_launch(void* const* d_in, const int* in_sizes, int n_in,
                              void* d_out, int out_size, void* d_ws, size_t ws_size,
                              hipStream_t stream) {
    const float* x        = (const float*)d_in[0];
    const float* norm1_g  = (const float*)d_in[1];
    const float* norm1_b  = (const float*)d_in[2];
    const float* fusion_w = (const float*)d_in[3];
    const float* prio_sc  = (const float*)d_in[4];
    const float* prio_of  = (const float*)d_in[5];
    const float* in_w     = (const float*)d_in[6];
    const float* in_b     = (const float*)d_in[7];
    const float* cpe_w    = (const float*)d_in[8];
    const float* cpe_b    = (const float*)d_in[9];
    const float* xproj_w  = (const float*)d_in[10];
    const float* dt_w     = (const float*)d_in[11];
    const float* dt_b     = (const float*)d_in[12];
    const float* A_logs   = (const float*)d_in[13];
    const float* Ds       = (const float*)d_in[14];
    const float* gC_w     = (const float*)d_in[15];
    const float* gC_b     = (const float*)d_in[16];
    const float* gC_wt    = (const float*)d_in[17];
    const float* outn_g   = (const float*)d_in[18];
    const float* outn_b   = (const float*)d_in[19];
    const float* outp_w   = (const float*)d_in[20];
    const float* outp_b   = (const float*)d_in[21];
    const float* norm2_g  = (const float*)d_in[22];
    const float* norm2_b  = (const float*)d_in[23];
    const float* mlp_w1   = (const float*)d_in[24];
    const float* mlp_b1   = (const float*)d_in[25];
    const float* mlp_w2   = (const float*)d_in[26];
    const float* mlp_b2   = (const float*)d_in[27];
    float* out = (float*)d_out;

    float* ws = (float*)d_ws;
    size_t off = 0;
    auto alloc = [&](size_t n) { float* p = ws + off; off += (n + 63) & ~(size_t)63; return p; };
    float* gray   = alloc(MROWS);
    float* gp     = alloc(MROWS);
    int*   idxb   = (int*)alloc(MROWS);
    int*   invb   = (int*)alloc(MROWS);
    float* xdbl   = alloc((size_t)MROWS * 32);              // [M,32]: B(0:16), C(16:32), f32
    short* wbig   = (short*)alloc((size_t)640 * HID / 2);   // bf16 [640,512]
    short* wbuf   = (short*)alloc(524288 / 2);              // bf16 weights (4 mats)
    short* xn     = (short*)alloc((size_t)MROWS * DIMC / 2);// LN(x) bf16
    float* sumd   = alloc((size_t)BSZ * NCH * HID);
    float* hend   = alloc((size_t)BSZ * NCH * 16 * HID);
    float* hstart = alloc((size_t)BSZ * NCH * 16 * HID);
    bf16*  bufA   = (bf16*)alloc((size_t)MROWS * HID / 2);  // xp -> delta -> yn -> h
    bf16*  bufB   = (bf16*)alloc((size_t)MROWS * HID / 2);  // sx -> y -> x1n
    float* bufC   = alloc((size_t)MROWS * DIMC);            // x1 (f32)
    if (off * sizeof(float) > ws_size) return;

    short* w_in  = wbuf;            // [512,256]
    short* w_out = wbuf + 131072;   // [256,512]
    short* w_m1  = wbuf + 262144;   // [512,256]
    short* w_m2  = wbuf + 393216;   // [256,512]

    // 0) weight prep (bf16)
    wcvt_k<<<(524288 + 255) / 256, 256, 0, stream>>>(in_w, outp_w, mlp_w1, mlp_w2, wbuf);
    wbig_k<<<640, 256, 0, stream>>>(dt_w, xproj_w, wbig);

    // 1) gray + gradient priority + sort
    gray_kernel<<<MROWS / 4, 256, 0, stream>>>(x, gray);
    grad_kernel<<<MROWS / 256, 256, 0, stream>>>(gray, gp, fusion_w);
    gp_kernel<<<BSZ, 1024, 0, stream>>>(gp, prio_sc, prio_of);
    sort_kernel<<<BSZ, 1024, 0, stream>>>(gp, idxb, invb);

    // 2) xn = LN(x) bf16; in_proj -> xp (bufA)
    normf_k<<<MROWS / 4, 256, 0, stream>>>(x, norm1_g, norm1_b, xn);
    mgemm<EP_BF><<<dim3(HID / 128, MROWS / 128), 256, 0, stream>>>(
        xn, DIMC, w_in, in_b, HID, DIMC, nullptr, nullptr, nullptr, nullptr, bufA);

    // 3) CPE depthwise conv + gate + gather -> sx (bufB)
    cpe_kernel<<<BSZ * 16 * 16, 256, 0, stream>>>(bufA, cpe_w, cpe_b, invb, bufB);

    // 4) combined delta + x_proj B/C GEMM: N=640 (512 delta | 32 BC | 96 pad)
    mgemm<EP_DELTAXBC><<<dim3(640 / 128, MROWS / 128), 256, 0, stream>>>(
        (const short*)bufB, HID, wbig, dt_b, 640, HID, nullptr, nullptr, nullptr, xdbl, bufA);
    gcfix_kernel<<<(MROWS * 16) / 256, 256, 0, stream>>>(xdbl, gp, gC_wt, gC_w, gC_b);

    // 5) chunk-parallel selective scan (y overwrites sx in bufB)
    scan_pass1<<<BSZ * NCH, 512, 0, stream>>>(bufA, bufB, xdbl, A_logs, hend, sumd);
    scan_combine<<<BSZ, 512, 0, stream>>>(hend, sumd, A_logs, hstart);
    scan_pass2<<<BSZ * NCH, 512, 0, stream>>>(bufA, bufB, xdbl, A_logs, Ds, hstart);

    // 6) yn = LN(y) bf16 (into bufA); out_proj + scatter + x residual -> x1 (bufC f32)
    normb_k<<<MROWS / 4, 256, 0, stream>>>((const short*)bufB, outn_g, outn_b, (short*)bufA);
    mgemm<EP_SCATTER><<<dim3(DIMC / 128, MROWS / 128), 256, 0, stream>>>(
        (const short*)bufA, HID, w_out, outp_b, DIMC, HID, idxb, x, nullptr, bufC, nullptr);

    // 7) MLP: x1n = LN(x1) bf16 (bufB); silu fc1 -> h (bufA); fc2 + x1 resid -> out
    normf_k<<<MROWS / 4, 256, 0, stream>>>(bufC, norm2_g, norm2_b, (short*)bufB);
    mgemm<EP_SILU><<<dim3(HID / 128, MROWS / 128), 256, 0, stream>>>(
        (const short*)bufB, DIMC, w_m1, mlp_b1, HID, DIMC, nullptr, nullptr, nullptr, nullptr, bufA);
    mgemm<EP_RESID><<<dim3(DIMC / 128, MROWS / 128), 256, 0, stream>>>(
        (const short*)bufA, HID, w_m2, mlp_b2, DIMC, HID, nullptr, nullptr, bufC, out, nullptr);
}

// Round 7
// 688.047 us; speedup vs baseline: 1.0462x; 1.0462x over previous
//
#include <hip/hip_runtime.h>
#include <hip/hip_bf16.h>

typedef __hip_bfloat16 bf16;

static constexpr int BSZ  = 8;
static constexpr int L    = 4096;
static constexpr int DIMC = 256;
static constexpr int HID  = 512;
static constexpr int NCH  = 64;   // scan chunks
static constexpr int CLEN = 64;   // steps per chunk
static constexpr int MROWS = BSZ * L; // 32768

typedef __attribute__((ext_vector_type(8))) short bf16x8;
typedef __attribute__((ext_vector_type(4))) short short4v;
typedef __attribute__((ext_vector_type(4))) float f32x4;

__device__ __forceinline__ short f2b(float f) {
    return __builtin_bit_cast(short, __float2bfloat16(f));
}
__device__ __forceinline__ float b2f(bf16 v) { return __bfloat162float(v); }
__device__ __forceinline__ float s2f(short s) {
    return __bfloat162float(__builtin_bit_cast(bf16, s));
}
__device__ __forceinline__ void gload_lds16(const void* g, void* l) {
    __builtin_amdgcn_global_load_lds(
        (const __attribute__((address_space(1))) unsigned int*)g,
        (__attribute__((address_space(3))) unsigned int*)l, 16, 0, 0);
}

// ---------------------------------------------------------------- gray mean
__global__ void gray_kernel(const float* __restrict__ x, float* __restrict__ gray) {
    int gid = blockIdx.x * blockDim.x + threadIdx.x;
    int wid = gid >> 6, lane = gid & 63;
    if (wid >= MROWS) return;
    float4 f = *(const float4*)(x + (size_t)wid * DIMC + lane * 4);
    float s = f.x + f.y + f.z + f.w;
    for (int o = 32; o; o >>= 1) s += __shfl_down(s, o);
    if (lane == 0) gray[wid] = s * (1.f / 256.f);
}

// ------------------------------------------------- sobel/laplacian + fusion
__global__ void grad_kernel(const float* __restrict__ gray, float* __restrict__ gm,
                            const float* __restrict__ fw) {
    int p = blockIdx.x * blockDim.x + threadIdx.x;
    if (p >= MROWS) return;
    int b = p >> 12, pp = p & 4095, h = pp >> 6, w = pp & 63;
    const float* g = gray + ((size_t)b << 12);
    auto G = [&](int hh, int ww) -> float {
        if (hh < 0 || hh > 63 || ww < 0 || ww > 63) return 0.f;
        return g[(hh << 6) + ww];
    };
    float g00=G(h-1,w-1), g01=G(h-1,w), g02=G(h-1,w+1);
    float g10=G(h,  w-1), g11=G(h,  w), g12=G(h,  w+1);
    float g20=G(h+1,w-1), g21=G(h+1,w), g22=G(h+1,w+1);
    float gx  = -g00 + g02 - 2.f*g10 + 2.f*g12 - g20 + g22;
    float gy  = -g00 - 2.f*g01 - g02 + g20 + 2.f*g21 + g22;
    float lap = 4.f*g11 - g01 - g10 - g12 - g21;
    float v = fw[0]*gx + fw[1]*gy + fw[2]*lap;
    gm[p] = fabsf(v);
}

// ------------------------------------------------ per-batch minmax + sigmoid
__global__ __launch_bounds__(1024) void gp_kernel(float* __restrict__ gmgp,
                                                  const float* __restrict__ sc_,
                                                  const float* __restrict__ of_) {
    int b = blockIdx.x, tid = threadIdx.x;
    float v[4], lmin = 3.4e38f, lmax = -3.4e38f;
    for (int i = 0; i < 4; i++) {
        v[i] = gmgp[(b << 12) + tid + (i << 10)];
        lmin = fminf(lmin, v[i]); lmax = fmaxf(lmax, v[i]);
    }
    for (int o = 32; o; o >>= 1) {
        lmin = fminf(lmin, __shfl_xor(lmin, o));
        lmax = fmaxf(lmax, __shfl_xor(lmax, o));
    }
    __shared__ float smin[16], smax[16];
    int wid = tid >> 6, lane = tid & 63;
    if (lane == 0) { smin[wid] = lmin; smax[wid] = lmax; }
    __syncthreads();
    if (tid == 0) {
        float a = smin[0], c = smax[0];
        for (int wv = 1; wv < 16; wv++) { a = fminf(a, smin[wv]); c = fmaxf(c, smax[wv]); }
        smin[0] = a; smax[0] = c;
    }
    __syncthreads();
    float gmin = smin[0], gmax = smax[0];
    float invd = 1.f / (gmax - gmin + 1e-8f);
    float sc = sc_[0], of = of_[0];
    for (int i = 0; i < 4; i++) {
        float z = sc * ((v[i] - gmin) * invd) + of;
        gmgp[(b << 12) + tid + (i << 10)] = 1.f / (1.f + __expf(-z));
    }
}

// -------------------------------------------- stable argsort (bitonic, u64)
__global__ __launch_bounds__(1024) void sort_kernel(const float* __restrict__ gp,
                                                    int* __restrict__ idx, int* __restrict__ inv) {
    __shared__ unsigned long long keys[4096];
    int b = blockIdx.x, tid = threadIdx.x;
    for (int i = tid; i < 4096; i += 1024) {
        unsigned int fb = __float_as_uint(gp[(b << 12) + i]);
        keys[i] = ((unsigned long long)fb << 32) | (unsigned int)i;
    }
    __syncthreads();
    for (int k = 2; k <= 4096; k <<= 1) {
        for (int j = k >> 1; j > 0; j >>= 1) {
            for (int i = tid; i < 4096; i += 1024) {
                int ixj = i ^ j;
                if (ixj > i) {
                    unsigned long long a = keys[i], c = keys[ixj];
                    bool up = ((i & k) == 0);
                    if ((a > c) == up) { keys[i] = c; keys[ixj] = a; }
                }
            }
            __syncthreads();
        }
    }
    for (int i = tid; i < 4096; i += 1024) {
        int p = (int)(keys[i] & 0xffffffffULL);
        idx[(b << 12) + i] = p;
        inv[(b << 12) + p] = i;
    }
}

// ------------------------------------- fused LN: f32[C=256] -> normalized bf16
__global__ void normf_k(const float* __restrict__ src, const float* __restrict__ g,
                        const float* __restrict__ b, short* __restrict__ dst) {
    int gid = blockIdx.x * blockDim.x + threadIdx.x;
    int wid = gid >> 6, lane = gid & 63;
    if (wid >= MROWS) return;
    float4 f = *(const float4*)(src + (size_t)wid * 256 + lane * 4);
    float v[4] = {f.x, f.y, f.z, f.w};
    float s = v[0] + v[1] + v[2] + v[3];
    for (int o = 32; o; o >>= 1) s += __shfl_xor(s, o);
    float mean = s * (1.f / 256.f);
    float q = 0.f;
    for (int i = 0; i < 4; i++) { float d = v[i] - mean; q += d * d; }
    for (int o = 32; o; o >>= 1) q += __shfl_xor(q, o);
    float rstd = rsqrtf(q * (1.f / 256.f) + 1e-5f);
    short4v ov;
    for (int i = 0; i < 4; i++)
        ov[i] = f2b((v[i] - mean) * rstd * g[lane * 4 + i] + b[lane * 4 + i]);
    *(short4v*)(dst + (size_t)wid * 256 + lane * 4) = ov;
}

// ------------------------------------- fused LN: bf16[C=512] -> normalized bf16
__global__ void normb_k(const short* __restrict__ src, const float* __restrict__ g,
                        const float* __restrict__ b, short* __restrict__ dst) {
    int gid = blockIdx.x * blockDim.x + threadIdx.x;
    int wid = gid >> 6, lane = gid & 63;
    if (wid >= MROWS) return;
    bf16x8 pk = *(const bf16x8*)(src + (size_t)wid * 512 + lane * 8);
    float v[8];
    for (int i = 0; i < 8; i++) v[i] = s2f(pk[i]);
    float s = 0.f;
    for (int i = 0; i < 8; i++) s += v[i];
    for (int o = 32; o; o >>= 1) s += __shfl_xor(s, o);
    float mean = s * (1.f / 512.f);
    float q = 0.f;
    for (int i = 0; i < 8; i++) { float d = v[i] - mean; q += d * d; }
    for (int o = 32; o; o >>= 1) q += __shfl_xor(q, o);
    float rstd = rsqrtf(q * (1.f / 512.f) + 1e-5f);
    bf16x8 ov;
    for (int i = 0; i < 8; i++)
        ov[i] = f2b((v[i] - mean) * rstd * g[lane * 8 + i] + b[lane * 8 + i]);
    *(bf16x8*)(dst + (size_t)wid * 512 + lane * 8) = ov;
}

// ---------------- W_big[640][512]: rows 0:512 = dt_w @ x_proj_w[0:32,:],
//                  rows 512:544 = x_proj_w[32:64,:], rows 544:640 = 0
__global__ void wbig_k(const float* __restrict__ dtw, const float* __restrict__ xpw,
                       short* __restrict__ wd) {
    int d = blockIdx.x;        // 640
    for (int kk = threadIdx.x; kk < HID; kk += 256) {
        float s = 0.f;
        if (d < 512) {
#pragma unroll
            for (int r = 0; r < 32; r++) s += dtw[d * 32 + r] * xpw[r * HID + kk];
        } else if (d < 544) {
            s = xpw[(d - 480) * HID + kk];
        }
        wd[(size_t)d * HID + kk] = f2b(s);
    }
}

// -------------------------------- convert 4 weight matrices to bf16 (once)
__global__ void wcvt_k(const float* __restrict__ s0, const float* __restrict__ s1,
                       const float* __restrict__ s2, const float* __restrict__ s3,
                       short* __restrict__ dst) {
    int g = blockIdx.x * blockDim.x + threadIdx.x;
    if (g >= 524288) return;
    float v;
    if      (g < 131072) v = s0[g];
    else if (g < 262144) v = s1[g - 131072];
    else if (g < 393216) v = s2[g - 262144];
    else                 v = s3[g - 393216];
    dst[g] = f2b(v);
}

// ------------------------------------------------------------ MFMA bf16 GEMM
// BM=BN=128, 4 waves 2x2, wave tile 64x64, BK=32.
// 2-stage pipeline: global_load_lds (width 16) into double-buffered LDS,
// one barrier per K-step; read-side swizzle via source-chunk permutation.
// 1-D grid NBX*256 with XCD-aware decode for A-panel L2 reuse.
enum { EP_BF = 0, EP_DELTAXBC = 1, EP_SILU = 2, EP_SCATTER = 3, EP_RESID = 4 };

template<int NBX, int KT, int EP>
__global__ __launch_bounds__(256) void mgemm(
    const short* __restrict__ A, int lda, const short* __restrict__ W,
    const float* __restrict__ bias, int N,
    const int* __restrict__ idx, const float* __restrict__ xres, const float* __restrict__ fres,
    float* __restrict__ outf, bf16* __restrict__ outb)
{
    __shared__ __align__(16) short As[2][128 * 32];
    __shared__ __align__(16) short Bs[2][128 * 32];

    const int t = threadIdx.x;
    const int id = blockIdx.x;
    const int xcd = id & 7, sl = id >> 3;
    const int bx = sl % NBX, byl = sl / NBX;
    const int m0 = (xcd * 32 + byl) << 7, n0 = bx << 7;

    const int w = t >> 6, lane = t & 63;
    const int wm0 = (w & 1) << 6, wn0 = (w >> 1) << 6;
    const int lrow = lane & 15, quad = lane >> 4;
    const int wbase = t & ~63;   // wave-uniform chunk base within 256

    // per-thread staging source coords (swizzled q so frag reads are ~conflict-free)
    int r0 = t >> 2, r1 = (256 + t) >> 2;
    int q0 = (t & 3) ^ ((r0 >> 1) & 3);
    int q1 = (t & 3) ^ ((r1 >> 1) & 3);
    const short* Asrc0 = A + (size_t)(m0 + r0) * lda + q0 * 8;
    const short* Asrc1 = A + (size_t)(m0 + r1) * lda + q1 * 8;
    const short* Wsrc0 = W + (size_t)(n0 + r0) * KT + q0 * 8;
    const short* Wsrc1 = W + (size_t)(n0 + r1) * KT + q1 * 8;

    constexpr int nK = KT / 32;
    f32x4 acc[4][4] = {};

    auto stage = [&](int k, int buf) {
        gload_lds16(Asrc0 + k * 32, &As[buf][wbase * 8]);
        gload_lds16(Asrc1 + k * 32, &As[buf][(256 + wbase) * 8]);
        gload_lds16(Wsrc0 + k * 32, &Bs[buf][wbase * 8]);
        gload_lds16(Wsrc1 + k * 32, &Bs[buf][(256 + wbase) * 8]);
    };

    stage(0, 0);
#pragma unroll
    for (int kk = 0; kk < nK; kk++) {
        __syncthreads();           // drains vmcnt -> tile kk ready
        const int cur = kk & 1;
        bf16x8 af[4], bfr[4];
#pragma unroll
        for (int f = 0; f < 4; f++) {
            int r = wm0 + f * 16 + lrow;
            af[f] = *(const bf16x8*)&As[cur][r * 32 + ((quad ^ ((r >> 1) & 3)) << 3)];
        }
#pragma unroll
        for (int g = 0; g < 4; g++) {
            int r = wn0 + g * 16 + lrow;
            bfr[g] = *(const bf16x8*)&Bs[cur][r * 32 + ((quad ^ ((r >> 1) & 3)) << 3)];
        }
        if (kk + 1 < nK) stage(kk + 1, 1 - cur);   // overlap with MFMAs below
#pragma unroll
        for (int f = 0; f < 4; f++)
#pragma unroll
            for (int g = 0; g < 4; g++)
                acc[f][g] = __builtin_amdgcn_mfma_f32_16x16x32_bf16(af[f], bfr[g], acc[f][g], 0, 0, 0);
    }

    // ---- epilogue ---- C/D: col = lane&15, row = quad*4 + reg
#pragma unroll
    for (int f = 0; f < 4; f++) {
#pragma unroll
        for (int g = 0; g < 4; g++) {
#pragma unroll
            for (int reg = 0; reg < 4; reg++) {
                int r = m0 + wm0 + f * 16 + quad * 4 + reg;
                int c = n0 + wn0 + g * 16 + lrow;
                float v = acc[f][g][reg];
                if (EP == EP_DELTAXBC) {
                    if (c < 512) {
                        v += bias[c];
                        v = (v > 20.f) ? v : log1pf(__expf(v));
                        outb[(size_t)r * HID + c] = __float2bfloat16(v);
                    } else if (c < 544) {
                        outf[(size_t)r * 32 + (c - 512)] = v;
                    }
                } else {
                    if (bias) v += bias[c];
                    if (EP == EP_SILU) v = v / (1.f + __expf(-v));
                    if (EP == EP_SCATTER) {
                        int bb = r >> 12;
                        int p = idx[r];
                        size_t o = (((size_t)bb << 12) + p) * (size_t)N + c;
                        outf[o] = xres[o] + v;
                    } else if (EP == EP_RESID) {
                        size_t o = (size_t)r * N + c;
                        outf[o] = fres[o] + v;
                    } else {
                        size_t o = (size_t)r * N + c;
                        if (EP == EP_SILU || EP == EP_BF) outb[o] = __float2bfloat16(v);
                    }
                }
            }
        }
    }
}

// --------------- depthwise 3x3 CPE + gate + gather (LDS-tiled, bf16 in/out)
__global__ __launch_bounds__(256) void cpe_kernel(const bf16* __restrict__ xp,
                                                  const float* __restrict__ cw,
                                                  const float* __restrict__ cb,
                                                  const int* __restrict__ inv,
                                                  bf16* __restrict__ sx) {
    __shared__ float4 smem[8 * 325];   // 8 ch-chunks x (18*18=324 +1 pad-stride)
    const int blk = blockIdx.x;
    const int cg = blk & 15, tile = (blk >> 4) & 15, b = blk >> 8;
    const int h0 = (tile >> 2) << 4, w0 = (tile & 3) << 4;
    const int cg0 = cg << 5;
    const int t = threadIdx.x;

    for (int i = 0; i < 11; i++) {
        int lin = i * 256 + t;
        if (lin < 2592) {
            int pix = lin >> 3, c = lin & 7;
            int hh = pix / 18, ww = pix - hh * 18;
            int gh = h0 + hh - 1, gw = w0 + ww - 1;
            float4 val = {0.f, 0.f, 0.f, 0.f};
            if (gh >= 0 && gh < 64 && gw >= 0 && gw < 64) {
                short4v s = *(const short4v*)((const short*)xp +
                    ((size_t)((b << 12) + (gh << 6) + gw)) * HID + cg0 + c * 4);
                val.x = s2f(s[0]); val.y = s2f(s[1]); val.z = s2f(s[2]); val.w = s2f(s[3]);
            }
            smem[c * 325 + pix] = val;
        }
    }
    __syncthreads();

    const int c = t & 7, pg = t >> 3;
    const int ch0 = cg0 + c * 4;
    float4 wk[9], cb4;
#pragma unroll
    for (int ki = 0; ki < 9; ki++) {
        wk[ki].x = cw[(ch0 + 0) * 9 + ki];
        wk[ki].y = cw[(ch0 + 1) * 9 + ki];
        wk[ki].z = cw[(ch0 + 2) * 9 + ki];
        wk[ki].w = cw[(ch0 + 3) * 9 + ki];
    }
    cb4.x = cb[ch0]; cb4.y = cb[ch0 + 1]; cb4.z = cb[ch0 + 2]; cb4.w = cb[ch0 + 3];

    for (int k = 0; k < 8; k++) {
        int pix = pg + k * 32;
        int h = pix >> 4, w = pix & 15;
        int hp = (h + 1) * 18 + (w + 1);
        float ax = 0.f, ay = 0.f, az = 0.f, aw = 0.f;
#pragma unroll
        for (int dh = -1; dh <= 1; dh++)
#pragma unroll
            for (int dw = -1; dw <= 1; dw++) {
                float4 v = smem[c * 325 + hp + dh * 18 + dw];
                float4 wt = wk[(dh + 1) * 3 + (dw + 1)];
                ax += v.x * wt.x; ay += v.y * wt.y; az += v.z * wt.z; aw += v.w * wt.w;
            }
        ax += cb4.x; ay += cb4.y; az += cb4.z; aw += cb4.w;
        float4 xv = smem[c * 325 + hp];
        short4v g;
        g[0] = f2b(xv.x / (1.f + __expf(-ax)));
        g[1] = f2b(xv.y / (1.f + __expf(-ay)));
        g[2] = f2b(xv.z / (1.f + __expf(-az)));
        g[3] = f2b(xv.w / (1.f + __expf(-aw)));
        int pglob = (b << 12) + ((h0 + h) << 6) + (w0 + w);
        int r = inv[pglob];
        *(short4v*)((short*)sx + ((size_t)((b << 12) + r)) * HID + ch0) = g;
    }
}

// ------------------------------------------------- gC fixup on C columns
__global__ void gcfix_kernel(float* __restrict__ xdbl, const float* __restrict__ gp,
                             const float* __restrict__ gw_, const float* __restrict__ gcw,
                             const float* __restrict__ gcb) {
    int i = blockIdx.x * blockDim.x + threadIdx.x; // 8*4096*16
    int s = i & 15, t = (i >> 4) & 4095, b = i >> 16;
    float gw = gw_[0];
    float gpv = gp[(b << 12) + (s << 8) + (t >> 4)];
    int tm = t & 15;
    xdbl[(((size_t)(b << 12) + t) << 5) + 16 + s] += gw * (gpv * gcw[tm] + gcb[tm]);
}

// ------------------------------------------------------ chunked scan pass 1
__global__ __launch_bounds__(512) void scan_pass1(const bf16* __restrict__ delta,
                                                  const bf16* __restrict__ sx,
                                                  const float* __restrict__ xdbl,
                                                  const float* __restrict__ A_logs,
                                                  float* __restrict__ h_end,
                                                  float* __restrict__ sumdelta) {
    __shared__ float Bsm[CLEN][16];
    int b = blockIdx.x >> 6, c = blockIdx.x & 63, d = threadIdx.x;
    int t0 = c << 6;
    for (int i = threadIdx.x; i < CLEN * 16; i += 512) {
        int row = i >> 4, col = i & 15;
        Bsm[row][col] = xdbl[(((size_t)(b << 12) + t0 + row) << 5) + col];
    }
    __syncthreads();
    float A[16];
#pragma unroll
    for (int s = 0; s < 16; s++) A[s] = -__expf(A_logs[d * 16 + s]);
    float h[16];
#pragma unroll
    for (int s = 0; s < 16; s++) h[s] = 0.f;
    float sumd = 0.f;
    for (int t = 0; t < CLEN; t++) {
        size_t ro = (((size_t)b << 12) + t0 + t) * HID + d;
        float dlt = b2f(delta[ro]), uu = b2f(sx[ro]);
        sumd += dlt;
        float du = dlt * uu;
#pragma unroll
        for (int s = 0; s < 16; s++) h[s] = __expf(A[s] * dlt) * h[s] + du * Bsm[t][s];
    }
    int cidx = blockIdx.x;
    sumdelta[(size_t)cidx * HID + d] = sumd;
#pragma unroll
    for (int s = 0; s < 16; s++) h_end[((size_t)cidx * 16 + s) * HID + d] = h[s];
}

// --------------------------------------------------- scan chunk combination
__global__ __launch_bounds__(512) void scan_combine(const float* __restrict__ h_end,
                                                    const float* __restrict__ sumdelta,
                                                    const float* __restrict__ A_logs,
                                                    float* __restrict__ h_start) {
    int b = blockIdx.x, d = threadIdx.x;
    float A[16];
#pragma unroll
    for (int s = 0; s < 16; s++) A[s] = -__expf(A_logs[d * 16 + s]);
    float carry[16];
#pragma unroll
    for (int s = 0; s < 16; s++) carry[s] = 0.f;
    for (int c = 0; c < NCH; c++) {
        int cidx = (b << 6) + c;
        float sd = sumdelta[(size_t)cidx * HID + d];
#pragma unroll
        for (int s = 0; s < 16; s++) {
            size_t o = ((size_t)cidx * 16 + s) * HID + d;
            h_start[o] = carry[s];
            carry[s] = __expf(A[s] * sd) * carry[s] + h_end[o];
        }
    }
}

// ------------------------------------------------------ chunked scan pass 2
__global__ __launch_bounds__(512) void scan_pass2(const bf16* __restrict__ delta,
                                                  bf16* __restrict__ sxy,  // in: sx, out: y
                                                  const float* __restrict__ xdbl,
                                                  const float* __restrict__ A_logs,
                                                  const float* __restrict__ Ds,
                                                  const float* __restrict__ h_start) {
    __shared__ float BC[CLEN][32];
    int b = blockIdx.x >> 6, c = blockIdx.x & 63, d = threadIdx.x;
    int t0 = c << 6;
    for (int i = threadIdx.x; i < CLEN * 32; i += 512) {
        int row = i >> 5, col = i & 31;
        BC[row][col] = xdbl[(((size_t)(b << 12) + t0 + row) << 5) + col];
    }
    __syncthreads();
    float A[16];
#pragma unroll
    for (int s = 0; s < 16; s++) A[s] = -__expf(A_logs[d * 16 + s]);
    int cidx = blockIdx.x;
    float h[16];
#pragma unroll
    for (int s = 0; s < 16; s++) h[s] = h_start[((size_t)cidx * 16 + s) * HID + d];
    float Dd = Ds[d];
    for (int t = 0; t < CLEN; t++) {
        size_t ro = (((size_t)b << 12) + t0 + t) * HID + d;
        float dlt = b2f(delta[ro]), uu = b2f(sxy[ro]);
        float du = dlt * uu;
        float acc = uu * Dd;
#pragma unroll
        for (int s = 0; s < 16; s++) {
            h[s] = __expf(A[s] * dlt) * h[s] + du * BC[t][s];
            acc += h[s] * BC[t][16 + s];
        }
        sxy[ro] = __float2bfloat16(acc);
    }
}

// ---------------------------------------------------------------- launcher
extern "C" void kernel_launch(void* const* d_in, const int* in_sizes, int n_in,
                              void* d_out, int out_size, void* d_ws, size_t ws_size,
                              hipStream_t stream) {
    const float* x        = (const float*)d_in[0];
    const float* norm1_g  = (const float*)d_in[1];
    const float* norm1_b  = (const float*)d_in[2];
    const float* fusion_w = (const float*)d_in[3];
    const float* prio_sc  = (const float*)d_in[4];
    const float* prio_of  = (const float*)d_in[5];
    const float* in_w     = (const float*)d_in[6];
    const float* in_b     = (const float*)d_in[7];
    const float* cpe_w    = (const float*)d_in[8];
    const float* cpe_b    = (const float*)d_in[9];
    const float* xproj_w  = (const float*)d_in[10];
    const float* dt_w     = (const float*)d_in[11];
    const float* dt_b     = (const float*)d_in[12];
    const float* A_logs   = (const float*)d_in[13];
    const float* Ds       = (const float*)d_in[14];
    const float* gC_w     = (const float*)d_in[15];
    const float* gC_b     = (const float*)d_in[16];
    const float* gC_wt    = (const float*)d_in[17];
    const float* outn_g   = (const float*)d_in[18];
    const float* outn_b   = (const float*)d_in[19];
    const float* outp_w   = (const float*)d_in[20];
    const float* outp_b   = (const float*)d_in[21];
    const float* norm2_g  = (const float*)d_in[22];
    const float* norm2_b  = (const float*)d_in[23];
    const float* mlp_w1   = (const float*)d_in[24];
    const float* mlp_b1   = (const float*)d_in[25];
    const float* mlp_w2   = (const float*)d_in[26];
    const float* mlp_b2   = (const float*)d_in[27];
    float* out = (float*)d_out;

    float* ws = (float*)d_ws;
    size_t off = 0;
    auto alloc = [&](size_t n) { float* p = ws + off; off += (n + 63) & ~(size_t)63; return p; };
    float* gray   = alloc(MROWS);
    float* gp     = alloc(MROWS);
    int*   idxb   = (int*)alloc(MROWS);
    int*   invb   = (int*)alloc(MROWS);
    float* xdbl   = alloc((size_t)MROWS * 32);              // [M,32]: B(0:16), C(16:32), f32
    short* wbig   = (short*)alloc((size_t)640 * HID / 2);   // bf16 [640,512]
    short* wbuf   = (short*)alloc(524288 / 2);              // bf16 weights (4 mats)
    short* xn     = (short*)alloc((size_t)MROWS * DIMC / 2);// LN(x) bf16
    float* sumd   = alloc((size_t)BSZ * NCH * HID);
    float* hend   = alloc((size_t)BSZ * NCH * 16 * HID);
    float* hstart = alloc((size_t)BSZ * NCH * 16 * HID);
    bf16*  bufA   = (bf16*)alloc((size_t)MROWS * HID / 2);  // xp -> delta -> yn -> h
    bf16*  bufB   = (bf16*)alloc((size_t)MROWS * HID / 2);  // sx -> y -> x1n
    float* bufC   = alloc((size_t)MROWS * DIMC);            // x1 (f32)
    if (off * sizeof(float) > ws_size) return;

    short* w_in  = wbuf;            // [512,256]
    short* w_out = wbuf + 131072;   // [256,512]
    short* w_m1  = wbuf + 262144;   // [512,256]
    short* w_m2  = wbuf + 393216;   // [256,512]

    // 0) weight prep (bf16)
    wcvt_k<<<(524288 + 255) / 256, 256, 0, stream>>>(in_w, outp_w, mlp_w1, mlp_w2, wbuf);
    wbig_k<<<640, 256, 0, stream>>>(dt_w, xproj_w, wbig);

    // 1) gray + gradient priority + sort
    gray_kernel<<<MROWS / 4, 256, 0, stream>>>(x, gray);
    grad_kernel<<<MROWS / 256, 256, 0, stream>>>(gray, gp, fusion_w);
    gp_kernel<<<BSZ, 1024, 0, stream>>>(gp, prio_sc, prio_of);
    sort_kernel<<<BSZ, 1024, 0, stream>>>(gp, idxb, invb);

    // 2) xn = LN(x) bf16; in_proj -> xp (bufA)
    normf_k<<<MROWS / 4, 256, 0, stream>>>(x, norm1_g, norm1_b, xn);
    mgemm<4, 256, EP_BF><<<4 * 256, 256, 0, stream>>>(
        xn, DIMC, w_in, in_b, HID, nullptr, nullptr, nullptr, nullptr, bufA);

    // 3) CPE depthwise conv + gate + gather -> sx (bufB)
    cpe_kernel<<<BSZ * 16 * 16, 256, 0, stream>>>(bufA, cpe_w, cpe_b, invb, bufB);

    // 4) combined delta + x_proj B/C GEMM: N=640 (512 delta | 32 BC | 96 pad)
    mgemm<5, 512, EP_DELTAXBC><<<5 * 256, 256, 0, stream>>>(
        (const short*)bufB, HID, wbig, dt_b, 640, nullptr, nullptr, nullptr, xdbl, bufA);
    gcfix_kernel<<<(MROWS * 16) / 256, 256, 0, stream>>>(xdbl, gp, gC_wt, gC_w, gC_b);

    // 5) chunk-parallel selective scan (y overwrites sx in bufB)
    scan_pass1<<<BSZ * NCH, 512, 0, stream>>>(bufA, bufB, xdbl, A_logs, hend, sumd);
    scan_combine<<<BSZ, 512, 0, stream>>>(hend, sumd, A_logs, hstart);
    scan_pass2<<<BSZ * NCH, 512, 0, stream>>>(bufA, bufB, xdbl, A_logs, Ds, hstart);

    // 6) yn = LN(y) bf16 (into bufA); out_proj + scatter + x residual -> x1 (bufC f32)
    normb_k<<<MROWS / 4, 256, 0, stream>>>((const short*)bufB, outn_g, outn_b, (short*)bufA);
    mgemm<2, 512, EP_SCATTER><<<2 * 256, 256, 0, stream>>>(
        (const short*)bufA, HID, w_out, outp_b, DIMC, idxb, x, nullptr, bufC, nullptr);

    // 7) MLP: x1n = LN(x1) bf16 (bufB); silu fc1 -> h (bufA); fc2 + x1 resid -> out
    normf_k<<<MROWS / 4, 256, 0, stream>>>(bufC, norm2_g, norm2_b, (short*)bufB);
    mgemm<4, 256, EP_SILU><<<4 * 256, 256, 0, stream>>>(
        (const short*)bufB, DIMC, w_m1, mlp_b1, HID, nullptr, nullptr, nullptr, nullptr, bufA);
    mgemm<2, 512, EP_RESID><<<2 * 256, 256, 0, stream>>>(
        (const short*)bufA, HID, w_m2, mlp_b2, DIMC, nullptr, nullptr, bufC, out, nullptr);
}

// Round 8
// 631.517 us; speedup vs baseline: 1.1399x; 1.0895x over previous
//
#include <hip/hip_runtime.h>
#include <hip/hip_bf16.h>

typedef __hip_bfloat16 bf16;

static constexpr int BSZ  = 8;
static constexpr int L    = 4096;
static constexpr int DIMC = 256;
static constexpr int HID  = 512;
static constexpr int NCH  = 64;   // scan chunks
static constexpr int CLEN = 64;   // steps per chunk
static constexpr int MROWS = BSZ * L; // 32768

typedef __attribute__((ext_vector_type(8))) short bf16x8;
typedef __attribute__((ext_vector_type(4))) short short4v;
typedef __attribute__((ext_vector_type(4))) float f32x4;

__device__ __forceinline__ short f2b(float f) {
    return __builtin_bit_cast(short, __float2bfloat16(f));
}
__device__ __forceinline__ float b2f(bf16 v) { return __bfloat162float(v); }
__device__ __forceinline__ float s2f(short s) {
    return __bfloat162float(__builtin_bit_cast(bf16, s));
}
__device__ __forceinline__ void gload_lds16(const void* g, void* l) {
    __builtin_amdgcn_global_load_lds(
        (const __attribute__((address_space(1))) unsigned int*)g,
        (__attribute__((address_space(3))) unsigned int*)l, 16, 0, 0);
}

// ---------------------------------------------------------------- gray mean
__global__ void gray_kernel(const float* __restrict__ x, float* __restrict__ gray) {
    int gid = blockIdx.x * blockDim.x + threadIdx.x;
    int wid = gid >> 6, lane = gid & 63;
    if (wid >= MROWS) return;
    float4 f = *(const float4*)(x + (size_t)wid * DIMC + lane * 4);
    float s = f.x + f.y + f.z + f.w;
    for (int o = 32; o; o >>= 1) s += __shfl_down(s, o);
    if (lane == 0) gray[wid] = s * (1.f / 256.f);
}

// ------------------------------------------------- sobel/laplacian + fusion
__global__ void grad_kernel(const float* __restrict__ gray, float* __restrict__ gm,
                            const float* __restrict__ fw) {
    int p = blockIdx.x * blockDim.x + threadIdx.x;
    if (p >= MROWS) return;
    int b = p >> 12, pp = p & 4095, h = pp >> 6, w = pp & 63;
    const float* g = gray + ((size_t)b << 12);
    auto G = [&](int hh, int ww) -> float {
        if (hh < 0 || hh > 63 || ww < 0 || ww > 63) return 0.f;
        return g[(hh << 6) + ww];
    };
    float g00=G(h-1,w-1), g01=G(h-1,w), g02=G(h-1,w+1);
    float g10=G(h,  w-1), g11=G(h,  w), g12=G(h,  w+1);
    float g20=G(h+1,w-1), g21=G(h+1,w), g22=G(h+1,w+1);
    float gx  = -g00 + g02 - 2.f*g10 + 2.f*g12 - g20 + g22;
    float gy  = -g00 - 2.f*g01 - g02 + g20 + 2.f*g21 + g22;
    float lap = 4.f*g11 - g01 - g10 - g12 - g21;
    float v = fw[0]*gx + fw[1]*gy + fw[2]*lap;
    gm[p] = fabsf(v);
}

// ------------------------------------------------ per-batch minmax + sigmoid
__global__ __launch_bounds__(1024) void gp_kernel(float* __restrict__ gmgp,
                                                  const float* __restrict__ sc_,
                                                  const float* __restrict__ of_) {
    int b = blockIdx.x, tid = threadIdx.x;
    float v[4], lmin = 3.4e38f, lmax = -3.4e38f;
    for (int i = 0; i < 4; i++) {
        v[i] = gmgp[(b << 12) + tid + (i << 10)];
        lmin = fminf(lmin, v[i]); lmax = fmaxf(lmax, v[i]);
    }
    for (int o = 32; o; o >>= 1) {
        lmin = fminf(lmin, __shfl_xor(lmin, o));
        lmax = fmaxf(lmax, __shfl_xor(lmax, o));
    }
    __shared__ float smin[16], smax[16];
    int wid = tid >> 6, lane = tid & 63;
    if (lane == 0) { smin[wid] = lmin; smax[wid] = lmax; }
    __syncthreads();
    if (tid == 0) {
        float a = smin[0], c = smax[0];
        for (int wv = 1; wv < 16; wv++) { a = fminf(a, smin[wv]); c = fmaxf(c, smax[wv]); }
        smin[0] = a; smax[0] = c;
    }
    __syncthreads();
    float gmin = smin[0], gmax = smax[0];
    float invd = 1.f / (gmax - gmin + 1e-8f);
    float sc = sc_[0], of = of_[0];
    for (int i = 0; i < 4; i++) {
        float z = sc * ((v[i] - gmin) * invd) + of;
        gmgp[(b << 12) + tid + (i << 10)] = 1.f / (1.f + __expf(-z));
    }
}

// -------------------------------------------- stable argsort (bitonic, u64)
__global__ __launch_bounds__(1024) void sort_kernel(const float* __restrict__ gp,
                                                    int* __restrict__ idx, int* __restrict__ inv) {
    __shared__ unsigned long long keys[4096];
    int b = blockIdx.x, tid = threadIdx.x;
    for (int i = tid; i < 4096; i += 1024) {
        unsigned int fb = __float_as_uint(gp[(b << 12) + i]);
        keys[i] = ((unsigned long long)fb << 32) | (unsigned int)i;
    }
    __syncthreads();
    for (int k = 2; k <= 4096; k <<= 1) {
        for (int j = k >> 1; j > 0; j >>= 1) {
            for (int i = tid; i < 4096; i += 1024) {
                int ixj = i ^ j;
                if (ixj > i) {
                    unsigned long long a = keys[i], c = keys[ixj];
                    bool up = ((i & k) == 0);
                    if ((a > c) == up) { keys[i] = c; keys[ixj] = a; }
                }
            }
            __syncthreads();
        }
    }
    for (int i = tid; i < 4096; i += 1024) {
        int p = (int)(keys[i] & 0xffffffffULL);
        idx[(b << 12) + i] = p;
        inv[(b << 12) + p] = i;
    }
}

// ------------------------------------- fused LN: f32[C=256] -> normalized bf16
__global__ void normf_k(const float* __restrict__ src, const float* __restrict__ g,
                        const float* __restrict__ b, short* __restrict__ dst) {
    int gid = blockIdx.x * blockDim.x + threadIdx.x;
    int wid = gid >> 6, lane = gid & 63;
    if (wid >= MROWS) return;
    float4 f = *(const float4*)(src + (size_t)wid * 256 + lane * 4);
    float v[4] = {f.x, f.y, f.z, f.w};
    float s = v[0] + v[1] + v[2] + v[3];
    for (int o = 32; o; o >>= 1) s += __shfl_xor(s, o);
    float mean = s * (1.f / 256.f);
    float q = 0.f;
    for (int i = 0; i < 4; i++) { float d = v[i] - mean; q += d * d; }
    for (int o = 32; o; o >>= 1) q += __shfl_xor(q, o);
    float rstd = rsqrtf(q * (1.f / 256.f) + 1e-5f);
    short4v ov;
    for (int i = 0; i < 4; i++)
        ov[i] = f2b((v[i] - mean) * rstd * g[lane * 4 + i] + b[lane * 4 + i]);
    *(short4v*)(dst + (size_t)wid * 256 + lane * 4) = ov;
}

// ------------------------------------- fused LN: bf16[C=512] -> normalized bf16
__global__ void normb_k(const short* __restrict__ src, const float* __restrict__ g,
                        const float* __restrict__ b, short* __restrict__ dst) {
    int gid = blockIdx.x * blockDim.x + threadIdx.x;
    int wid = gid >> 6, lane = gid & 63;
    if (wid >= MROWS) return;
    bf16x8 pk = *(const bf16x8*)(src + (size_t)wid * 512 + lane * 8);
    float v[8];
    for (int i = 0; i < 8; i++) v[i] = s2f(pk[i]);
    float s = 0.f;
    for (int i = 0; i < 8; i++) s += v[i];
    for (int o = 32; o; o >>= 1) s += __shfl_xor(s, o);
    float mean = s * (1.f / 512.f);
    float q = 0.f;
    for (int i = 0; i < 8; i++) { float d = v[i] - mean; q += d * d; }
    for (int o = 32; o; o >>= 1) q += __shfl_xor(q, o);
    float rstd = rsqrtf(q * (1.f / 512.f) + 1e-5f);
    bf16x8 ov;
    for (int i = 0; i < 8; i++)
        ov[i] = f2b((v[i] - mean) * rstd * g[lane * 8 + i] + b[lane * 8 + i]);
    *(bf16x8*)(dst + (size_t)wid * 512 + lane * 8) = ov;
}

// ---------------- W_big[640][512]: rows 0:512 = dt_w @ x_proj_w[0:32,:],
//                  rows 512:544 = x_proj_w[32:64,:], rows 544:640 = 0
__global__ void wbig_k(const float* __restrict__ dtw, const float* __restrict__ xpw,
                       short* __restrict__ wd) {
    int d = blockIdx.x;        // 640
    for (int kk = threadIdx.x; kk < HID; kk += 256) {
        float s = 0.f;
        if (d < 512) {
#pragma unroll
            for (int r = 0; r < 32; r++) s += dtw[d * 32 + r] * xpw[r * HID + kk];
        } else if (d < 544) {
            s = xpw[(d - 480) * HID + kk];
        }
        wd[(size_t)d * HID + kk] = f2b(s);
    }
}

// -------------------------------- convert 4 weight matrices to bf16 (once)
__global__ void wcvt_k(const float* __restrict__ s0, const float* __restrict__ s1,
                       const float* __restrict__ s2, const float* __restrict__ s3,
                       short* __restrict__ dst) {
    int g = blockIdx.x * blockDim.x + threadIdx.x;
    if (g >= 524288) return;
    float v;
    if      (g < 131072) v = s0[g];
    else if (g < 262144) v = s1[g - 131072];
    else if (g < 393216) v = s2[g - 262144];
    else                 v = s3[g - 393216];
    dst[g] = f2b(v);
}

// ------------------------------------------------------------ MFMA bf16 GEMM
// BM=BN=128, 4 waves 2x2, wave tile 64x64, BK=32.
// 2-stage pipeline via global_load_lds double-buffered LDS; read-side swizzle.
// OPERAND-SWAPPED MFMA: mfma(W-frag, A-frag) so each lane's 4 acc regs are
// 4 CONSECUTIVE output channels of one row -> packed 8B/16B epilogue stores.
enum { EP_BF = 0, EP_DELTAXBC = 1, EP_SILU = 2, EP_SCATTER = 3, EP_RESID = 4 };

template<int NBX, int KT, int EP>
__global__ __launch_bounds__(256) void mgemm(
    const short* __restrict__ A, int lda, const short* __restrict__ W,
    const float* __restrict__ bias, int N,
    const int* __restrict__ idx, const float* __restrict__ xres, const float* __restrict__ fres,
    float* __restrict__ outf, bf16* __restrict__ outb)
{
    __shared__ __align__(16) short As[2][128 * 32];
    __shared__ __align__(16) short Bs[2][128 * 32];

    const int t = threadIdx.x;
    const int id = blockIdx.x;
    const int xcd = id & 7, sl = id >> 3;
    const int bx = sl % NBX, byl = sl / NBX;
    const int m0 = (xcd * 32 + byl) << 7, n0 = bx << 7;

    const int w = t >> 6, lane = t & 63;
    const int wm0 = (w & 1) << 6, wn0 = (w >> 1) << 6;
    const int lrow = lane & 15, quad = lane >> 4;
    const int wbase = t & ~63;   // wave-uniform chunk base within 256

    // per-thread staging source coords (swizzled q so frag reads are ~conflict-free)
    int r0 = t >> 2, r1 = (256 + t) >> 2;
    int q0 = (t & 3) ^ ((r0 >> 1) & 3);
    int q1 = (t & 3) ^ ((r1 >> 1) & 3);
    const short* Asrc0 = A + (size_t)(m0 + r0) * lda + q0 * 8;
    const short* Asrc1 = A + (size_t)(m0 + r1) * lda + q1 * 8;
    const short* Wsrc0 = W + (size_t)(n0 + r0) * KT + q0 * 8;
    const short* Wsrc1 = W + (size_t)(n0 + r1) * KT + q1 * 8;

    constexpr int nK = KT / 32;
    f32x4 acc[4][4] = {};

    auto stage = [&](int k, int buf) {
        gload_lds16(Asrc0 + k * 32, &As[buf][wbase * 8]);
        gload_lds16(Asrc1 + k * 32, &As[buf][(256 + wbase) * 8]);
        gload_lds16(Wsrc0 + k * 32, &Bs[buf][wbase * 8]);
        gload_lds16(Wsrc1 + k * 32, &Bs[buf][(256 + wbase) * 8]);
    };

    stage(0, 0);
#pragma unroll
    for (int kk = 0; kk < nK; kk++) {
        __syncthreads();           // drains vmcnt -> tile kk ready
        const int cur = kk & 1;
        bf16x8 af[4], bfr[4];
#pragma unroll
        for (int f = 0; f < 4; f++) {
            int r = wm0 + f * 16 + lrow;
            af[f] = *(const bf16x8*)&As[cur][r * 32 + ((quad ^ ((r >> 1) & 3)) << 3)];
        }
#pragma unroll
        for (int g = 0; g < 4; g++) {
            int r = wn0 + g * 16 + lrow;
            bfr[g] = *(const bf16x8*)&Bs[cur][r * 32 + ((quad ^ ((r >> 1) & 3)) << 3)];
        }
        if (kk + 1 < nK) stage(kk + 1, 1 - cur);   // overlap with MFMAs below
#pragma unroll
        for (int f = 0; f < 4; f++)
#pragma unroll
            for (int g = 0; g < 4; g++)   // swapped operands: D[chan][row]
                acc[f][g] = __builtin_amdgcn_mfma_f32_16x16x32_bf16(bfr[g], af[f], acc[f][g], 0, 0, 0);
    }

    // ---- packed epilogue ----
    // row  = m0 + wm0 + f*16 + (lane&15)
    // chan = n0 + wn0 + g*16 + quad*4 + reg  (4 consecutive chans per acc reg set)
#pragma unroll
    for (int f = 0; f < 4; f++) {
        int row = m0 + wm0 + f * 16 + lrow;
#pragma unroll
        for (int g = 0; g < 4; g++) {
            int ch = n0 + wn0 + g * 16 + quad * 4;
            f32x4 v4 = acc[f][g];
            if (EP == EP_DELTAXBC) {
                if (ch < 512) {
                    float4 b4 = *(const float4*)&bias[ch];
                    float vv[4] = {v4[0] + b4.x, v4[1] + b4.y, v4[2] + b4.z, v4[3] + b4.w};
                    short4v ov;
#pragma unroll
                    for (int i = 0; i < 4; i++) {
                        float sp = (vv[i] > 20.f) ? vv[i] : log1pf(__expf(vv[i]));
                        ov[i] = f2b(sp);
                    }
                    *(short4v*)((short*)outb + (size_t)row * HID + ch) = ov;
                } else if (ch < 544) {
                    *(f32x4*)(outf + (size_t)row * 32 + (ch - 512)) = v4;
                }
            } else {
                if (bias) {
                    float4 b4 = *(const float4*)&bias[ch];
                    v4[0] += b4.x; v4[1] += b4.y; v4[2] += b4.z; v4[3] += b4.w;
                }
                if (EP == EP_SILU) {
#pragma unroll
                    for (int i = 0; i < 4; i++) v4[i] = v4[i] / (1.f + __expf(-v4[i]));
                }
                if (EP == EP_SCATTER) {
                    int bb = row >> 12;
                    int p = idx[row];
                    size_t o = (((size_t)bb << 12) + p) * (size_t)N + ch;
                    float4 xr = *(const float4*)(xres + o);
                    float4 ov = {xr.x + v4[0], xr.y + v4[1], xr.z + v4[2], xr.w + v4[3]};
                    *(float4*)(outf + o) = ov;
                } else if (EP == EP_RESID) {
                    size_t o = (size_t)row * N + ch;
                    float4 fr = *(const float4*)(fres + o);
                    float4 ov = {fr.x + v4[0], fr.y + v4[1], fr.z + v4[2], fr.w + v4[3]};
                    *(float4*)(outf + o) = ov;
                } else {  // EP_BF / EP_SILU packed bf16 store
                    short4v ov;
#pragma unroll
                    for (int i = 0; i < 4; i++) ov[i] = f2b(v4[i]);
                    *(short4v*)((short*)outb + (size_t)row * N + ch) = ov;
                }
                if (EP == EP_SILU) {
                    // handled by packed store above (fallthrough shared with EP_BF)
                }
            }
        }
    }
}

// --------------- depthwise 3x3 CPE + gate + gather (LDS-tiled, bf16 in/out)
__global__ __launch_bounds__(256) void cpe_kernel(const bf16* __restrict__ xp,
                                                  const float* __restrict__ cw,
                                                  const float* __restrict__ cb,
                                                  const int* __restrict__ inv,
                                                  bf16* __restrict__ sx) {
    __shared__ float4 smem[8 * 325];   // 8 ch-chunks x (18*18=324 +1 pad-stride)
    const int blk = blockIdx.x;
    const int cg = blk & 15, tile = (blk >> 4) & 15, b = blk >> 8;
    const int h0 = (tile >> 2) << 4, w0 = (tile & 3) << 4;
    const int cg0 = cg << 5;
    const int t = threadIdx.x;

    for (int i = 0; i < 11; i++) {
        int lin = i * 256 + t;
        if (lin < 2592) {
            int pix = lin >> 3, c = lin & 7;
            int hh = pix / 18, ww = pix - hh * 18;
            int gh = h0 + hh - 1, gw = w0 + ww - 1;
            float4 val = {0.f, 0.f, 0.f, 0.f};
            if (gh >= 0 && gh < 64 && gw >= 0 && gw < 64) {
                short4v s = *(const short4v*)((const short*)xp +
                    ((size_t)((b << 12) + (gh << 6) + gw)) * HID + cg0 + c * 4);
                val.x = s2f(s[0]); val.y = s2f(s[1]); val.z = s2f(s[2]); val.w = s2f(s[3]);
            }
            smem[c * 325 + pix] = val;
        }
    }
    __syncthreads();

    const int c = t & 7, pg = t >> 3;
    const int ch0 = cg0 + c * 4;
    float4 wk[9], cb4;
#pragma unroll
    for (int ki = 0; ki < 9; ki++) {
        wk[ki].x = cw[(ch0 + 0) * 9 + ki];
        wk[ki].y = cw[(ch0 + 1) * 9 + ki];
        wk[ki].z = cw[(ch0 + 2) * 9 + ki];
        wk[ki].w = cw[(ch0 + 3) * 9 + ki];
    }
    cb4.x = cb[ch0]; cb4.y = cb[ch0 + 1]; cb4.z = cb[ch0 + 2]; cb4.w = cb[ch0 + 3];

    for (int k = 0; k < 8; k++) {
        int pix = pg + k * 32;
        int h = pix >> 4, w = pix & 15;
        int hp = (h + 1) * 18 + (w + 1);
        float ax = 0.f, ay = 0.f, az = 0.f, aw = 0.f;
#pragma unroll
        for (int dh = -1; dh <= 1; dh++)
#pragma unroll
            for (int dw = -1; dw <= 1; dw++) {
                float4 v = smem[c * 325 + hp + dh * 18 + dw];
                float4 wt = wk[(dh + 1) * 3 + (dw + 1)];
                ax += v.x * wt.x; ay += v.y * wt.y; az += v.z * wt.z; aw += v.w * wt.w;
            }
        ax += cb4.x; ay += cb4.y; az += cb4.z; aw += cb4.w;
        float4 xv = smem[c * 325 + hp];
        short4v g;
        g[0] = f2b(xv.x / (1.f + __expf(-ax)));
        g[1] = f2b(xv.y / (1.f + __expf(-ay)));
        g[2] = f2b(xv.z / (1.f + __expf(-az)));
        g[3] = f2b(xv.w / (1.f + __expf(-aw)));
        int pglob = (b << 12) + ((h0 + h) << 6) + (w0 + w);
        int r = inv[pglob];
        *(short4v*)((short*)sx + ((size_t)((b << 12) + r)) * HID + ch0) = g;
    }
}

// ------------------------------------------------- gC fixup on C columns
__global__ void gcfix_kernel(float* __restrict__ xdbl, const float* __restrict__ gp,
                             const float* __restrict__ gw_, const float* __restrict__ gcw,
                             const float* __restrict__ gcb) {
    int i = blockIdx.x * blockDim.x + threadIdx.x; // 8*4096*16
    int s = i & 15, t = (i >> 4) & 4095, b = i >> 16;
    float gw = gw_[0];
    float gpv = gp[(b << 12) + (s << 8) + (t >> 4)];
    int tm = t & 15;
    xdbl[(((size_t)(b << 12) + t) << 5) + 16 + s] += gw * (gpv * gcw[tm] + gcb[tm]);
}

// ------------------------------------------------------ chunked scan pass 1
__global__ __launch_bounds__(512) void scan_pass1(const bf16* __restrict__ delta,
                                                  const bf16* __restrict__ sx,
                                                  const float* __restrict__ xdbl,
                                                  const float* __restrict__ A_logs,
                                                  float* __restrict__ h_end,
                                                  float* __restrict__ sumdelta) {
    __shared__ float Bsm[CLEN][16];
    int b = blockIdx.x >> 6, c = blockIdx.x & 63, d = threadIdx.x;
    int t0 = c << 6;
    for (int i = threadIdx.x; i < CLEN * 16; i += 512) {
        int row = i >> 4, col = i & 15;
        Bsm[row][col] = xdbl[(((size_t)(b << 12) + t0 + row) << 5) + col];
    }
    __syncthreads();
    float A[16];
#pragma unroll
    for (int s = 0; s < 16; s++) A[s] = -__expf(A_logs[d * 16 + s]);
    float h[16];
#pragma unroll
    for (int s = 0; s < 16; s++) h[s] = 0.f;
    float sumd = 0.f;
    for (int t = 0; t < CLEN; t++) {
        size_t ro = (((size_t)b << 12) + t0 + t) * HID + d;
        float dlt = b2f(delta[ro]), uu = b2f(sx[ro]);
        sumd += dlt;
        float du = dlt * uu;
#pragma unroll
        for (int s = 0; s < 16; s++) h[s] = __expf(A[s] * dlt) * h[s] + du * Bsm[t][s];
    }
    int cidx = blockIdx.x;
    sumdelta[(size_t)cidx * HID + d] = sumd;
#pragma unroll
    for (int s = 0; s < 16; s++) h_end[((size_t)cidx * 16 + s) * HID + d] = h[s];
}

// --------------------------------------------------- scan chunk combination
__global__ __launch_bounds__(512) void scan_combine(const float* __restrict__ h_end,
                                                    const float* __restrict__ sumdelta,
                                                    const float* __restrict__ A_logs,
                                                    float* __restrict__ h_start) {
    int b = blockIdx.x, d = threadIdx.x;
    float A[16];
#pragma unroll
    for (int s = 0; s < 16; s++) A[s] = -__expf(A_logs[d * 16 + s]);
    float carry[16];
#pragma unroll
    for (int s = 0; s < 16; s++) carry[s] = 0.f;
    for (int c = 0; c < NCH; c++) {
        int cidx = (b << 6) + c;
        float sd = sumdelta[(size_t)cidx * HID + d];
#pragma unroll
        for (int s = 0; s < 16; s++) {
            size_t o = ((size_t)cidx * 16 + s) * HID + d;
            h_start[o] = carry[s];
            carry[s] = __expf(A[s] * sd) * carry[s] + h_end[o];
        }
    }
}

// ------------------------------------------------------ chunked scan pass 2
__global__ __launch_bounds__(512) void scan_pass2(const bf16* __restrict__ delta,
                                                  bf16* __restrict__ sxy,  // in: sx, out: y
                                                  const float* __restrict__ xdbl,
                                                  const float* __restrict__ A_logs,
                                                  const float* __restrict__ Ds,
                                                  const float* __restrict__ h_start) {
    __shared__ float BC[CLEN][32];
    int b = blockIdx.x >> 6, c = blockIdx.x & 63, d = threadIdx.x;
    int t0 = c << 6;
    for (int i = threadIdx.x; i < CLEN * 32; i += 512) {
        int row = i >> 5, col = i & 31;
        BC[row][col] = xdbl[(((size_t)(b << 12) + t0 + row) << 5) + col];
    }
    __syncthreads();
    float A[16];
#pragma unroll
    for (int s = 0; s < 16; s++) A[s] = -__expf(A_logs[d * 16 + s]);
    int cidx = blockIdx.x;
    float h[16];
#pragma unroll
    for (int s = 0; s < 16; s++) h[s] = h_start[((size_t)cidx * 16 + s) * HID + d];
    float Dd = Ds[d];
    for (int t = 0; t < CLEN; t++) {
        size_t ro = (((size_t)b << 12) + t0 + t) * HID + d;
        float dlt = b2f(delta[ro]), uu = b2f(sxy[ro]);
        float du = dlt * uu;
        float acc = uu * Dd;
#pragma unroll
        for (int s = 0; s < 16; s++) {
            h[s] = __expf(A[s] * dlt) * h[s] + du * BC[t][s];
            acc += h[s] * BC[t][16 + s];
        }
        sxy[ro] = __float2bfloat16(acc);
    }
}

// ---------------------------------------------------------------- launcher
extern "C" void kernel_launch(void* const* d_in, const int* in_sizes, int n_in,
                              void* d_out, int out_size, void* d_ws, size_t ws_size,
                              hipStream_t stream) {
    const float* x        = (const float*)d_in[0];
    const float* norm1_g  = (const float*)d_in[1];
    const float* norm1_b  = (const float*)d_in[2];
    const float* fusion_w = (const float*)d_in[3];
    const float* prio_sc  = (const float*)d_in[4];
    const float* prio_of  = (const float*)d_in[5];
    const float* in_w     = (const float*)d_in[6];
    const float* in_b     = (const float*)d_in[7];
    const float* cpe_w    = (const float*)d_in[8];
    const float* cpe_b    = (const float*)d_in[9];
    const float* xproj_w  = (const float*)d_in[10];
    const float* dt_w     = (const float*)d_in[11];
    const float* dt_b     = (const float*)d_in[12];
    const float* A_logs   = (const float*)d_in[13];
    const float* Ds       = (const float*)d_in[14];
    const float* gC_w     = (const float*)d_in[15];
    const float* gC_b     = (const float*)d_in[16];
    const float* gC_wt    = (const float*)d_in[17];
    const float* outn_g   = (const float*)d_in[18];
    const float* outn_b   = (const float*)d_in[19];
    const float* outp_w   = (const float*)d_in[20];
    const float* outp_b   = (const float*)d_in[21];
    const float* norm2_g  = (const float*)d_in[22];
    const float* norm2_b  = (const float*)d_in[23];
    const float* mlp_w1   = (const float*)d_in[24];
    const float* mlp_b1   = (const float*)d_in[25];
    const float* mlp_w2   = (const float*)d_in[26];
    const float* mlp_b2   = (const float*)d_in[27];
    float* out = (float*)d_out;

    float* ws = (float*)d_ws;
    size_t off = 0;
    auto alloc = [&](size_t n) { float* p = ws + off; off += (n + 63) & ~(size_t)63; return p; };
    float* gray   = alloc(MROWS);
    float* gp     = alloc(MROWS);
    int*   idxb   = (int*)alloc(MROWS);
    int*   invb   = (int*)alloc(MROWS);
    float* xdbl   = alloc((size_t)MROWS * 32);              // [M,32]: B(0:16), C(16:32), f32
    short* wbig   = (short*)alloc((size_t)640 * HID / 2);   // bf16 [640,512]
    short* wbuf   = (short*)alloc(524288 / 2);              // bf16 weights (4 mats)
    short* xn     = (short*)alloc((size_t)MROWS * DIMC / 2);// LN(x) bf16
    float* sumd   = alloc((size_t)BSZ * NCH * HID);
    float* hend   = alloc((size_t)BSZ * NCH * 16 * HID);
    float* hstart = alloc((size_t)BSZ * NCH * 16 * HID);
    bf16*  bufA   = (bf16*)alloc((size_t)MROWS * HID / 2);  // xp -> delta -> yn -> h
    bf16*  bufB   = (bf16*)alloc((size_t)MROWS * HID / 2);  // sx -> y -> x1n
    float* bufC   = alloc((size_t)MROWS * DIMC);            // x1 (f32)
    if (off * sizeof(float) > ws_size) return;

    short* w_in  = wbuf;            // [512,256]
    short* w_out = wbuf + 131072;   // [256,512]
    short* w_m1  = wbuf + 262144;   // [512,256]
    short* w_m2  = wbuf + 393216;   // [256,512]

    // 0) weight prep (bf16)
    wcvt_k<<<(524288 + 255) / 256, 256, 0, stream>>>(in_w, outp_w, mlp_w1, mlp_w2, wbuf);
    wbig_k<<<640, 256, 0, stream>>>(dt_w, xproj_w, wbig);

    // 1) gray + gradient priority + sort
    gray_kernel<<<MROWS / 4, 256, 0, stream>>>(x, gray);
    grad_kernel<<<MROWS / 256, 256, 0, stream>>>(gray, gp, fusion_w);
    gp_kernel<<<BSZ, 1024, 0, stream>>>(gp, prio_sc, prio_of);
    sort_kernel<<<BSZ, 1024, 0, stream>>>(gp, idxb, invb);

    // 2) xn = LN(x) bf16; in_proj -> xp (bufA)
    normf_k<<<MROWS / 4, 256, 0, stream>>>(x, norm1_g, norm1_b, xn);
    mgemm<4, 256, EP_BF><<<4 * 256, 256, 0, stream>>>(
        xn, DIMC, w_in, in_b, HID, nullptr, nullptr, nullptr, nullptr, bufA);

    // 3) CPE depthwise conv + gate + gather -> sx (bufB)
    cpe_kernel<<<BSZ * 16 * 16, 256, 0, stream>>>(bufA, cpe_w, cpe_b, invb, bufB);

    // 4) combined delta + x_proj B/C GEMM: N=640 (512 delta | 32 BC | 96 pad)
    mgemm<5, 512, EP_DELTAXBC><<<5 * 256, 256, 0, stream>>>(
        (const short*)bufB, HID, wbig, dt_b, 640, nullptr, nullptr, nullptr, xdbl, bufA);
    gcfix_kernel<<<(MROWS * 16) / 256, 256, 0, stream>>>(xdbl, gp, gC_wt, gC_w, gC_b);

    // 5) chunk-parallel selective scan (y overwrites sx in bufB)
    scan_pass1<<<BSZ * NCH, 512, 0, stream>>>(bufA, bufB, xdbl, A_logs, hend, sumd);
    scan_combine<<<BSZ, 512, 0, stream>>>(hend, sumd, A_logs, hstart);
    scan_pass2<<<BSZ * NCH, 512, 0, stream>>>(bufA, bufB, xdbl, A_logs, Ds, hstart);

    // 6) yn = LN(y) bf16 (into bufA); out_proj + scatter + x residual -> x1 (bufC f32)
    normb_k<<<MROWS / 4, 256, 0, stream>>>((const short*)bufB, outn_g, outn_b, (short*)bufA);
    mgemm<2, 512, EP_SCATTER><<<2 * 256, 256, 0, stream>>>(
        (const short*)bufA, HID, w_out, outp_b, DIMC, idxb, x, nullptr, bufC, nullptr);

    // 7) MLP: x1n = LN(x1) bf16 (bufB); silu fc1 -> h (bufA); fc2 + x1 resid -> out
    normf_k<<<MROWS / 4, 256, 0, stream>>>(bufC, norm2_g, norm2_b, (short*)bufB);
    mgemm<4, 256, EP_SILU><<<4 * 256, 256, 0, stream>>>(
        (const short*)bufB, DIMC, w_m1, mlp_b1, HID, nullptr, nullptr, nullptr, nullptr, bufA);
    mgemm<2, 512, EP_RESID><<<2 * 256, 256, 0, stream>>>(
        (const short*)bufA, HID, w_m2, mlp_b2, DIMC, nullptr, nullptr, bufC, out, nullptr);
}